// Round 14
// baseline (195.519 us; speedup 1.0000x reference)
//
#include <hip/hip_runtime.h>
#include <hip/hip_bf16.h>

typedef __bf16 bf16x8 __attribute__((ext_vector_type(8)));
typedef float f32x4 __attribute__((ext_vector_type(4)));
typedef float f32x2 __attribute__((ext_vector_type(2)));

#define MT 64   // tokens per block
#define CC 256

// swizzled LDS byte offset, [.][256] bf16 tile (row stride 512B)
__device__ __forceinline__ int swz(int r, int c) {
    return r * 512 + ((c * 2) ^ ((r & 7) << 4));
}
// swizzled LDS byte offset, [.][512] bf16 tile (row stride 1024B)
__device__ __forceinline__ int swzH(int r, int c) {
    return r * 1024 + ((c * 2) ^ ((r & 7) << 4));
}

// packed-B fragment load: tile (nc, kc) of 16 cols x 32 k, 1KB contiguous
__device__ __forceinline__ bf16x8 ldB(const __bf16* __restrict__ WT, int nc, int KC, int kc,
                                      int laneoff) {
    return *(const bf16x8*)(WT + ((size_t)nc * KC + kc) * 512 + laneoff);
}

// 1024-thread staging of a 64x256 fp32 tile: 4 f32x4 per thread (NT loads)
__device__ __forceinline__ void stage_load(const float* __restrict__ src, int row0, int tid,
                                           f32x4 (&v)[4]) {
#pragma unroll
    for (int i = 0; i < 4; ++i) {
        int f = i * 1024 + tid;
        int r = f >> 6;
        int c = (f & 63) * 4;
        v[i] = __builtin_nontemporal_load((const f32x4*)(src + (size_t)(row0 + r) * CC + c));
    }
}
__device__ __forceinline__ void stage_write(__bf16* dst, int tid, const f32x4 (&v)[4]) {
#pragma unroll
    for (int i = 0; i < 4; ++i) {
        int f = i * 1024 + tid;
        int r = f >> 6;
        int c = (f & 63) * 4;
        union { __bf16 h[4]; unsigned long long u; } uu;
        uu.h[0] = (__bf16)v[i][0]; uu.h[1] = (__bf16)v[i][1];
        uu.h[2] = (__bf16)v[i][2]; uu.h[3] = (__bf16)v[i][3];
        *(unsigned long long*)((char*)dst + swz(r, c)) = uu.u;
    }
}

// weight prep: transpose + bf16 + FRAGMENT-PACK (16col x 32k tiles = 1KB contiguous,
// element order lane*8+e). layout (bf16 elem offsets):
//   WTqp @0 (K=512,N=256: k<256 Wq else Wpos) | WTkp @131072 (Wk/Wpos)
//   WTo1 @262144 (K=256,N=512) | WTo2 @393216 (K=512,N=64)
//   WTv @425984 (K=256,N=256) | WTout @491520 (K=256,N=256)
__global__ void prep_all(const float* __restrict__ Wq, const float* __restrict__ Wk,
                         const float* __restrict__ Wpos, const float* __restrict__ Wo1,
                         const float* __restrict__ Wo2, const float* __restrict__ Wv,
                         const float* __restrict__ Wout, __bf16* __restrict__ ws)
{
    int i = blockIdx.x * 256 + threadIdx.x;
    if (i >= 557056) return;
    int j, K, N;
    const float* S0 = nullptr; const float* S1 = nullptr;
    if (i < 131072)      { j = i;          K = 512; N = 256; S0 = Wq;  S1 = Wpos; }
    else if (i < 262144) { j = i - 131072; K = 512; N = 256; S0 = Wk;  S1 = Wpos; }
    else if (i < 393216) { j = i - 262144; K = 256; N = 512; S0 = Wo1; }
    else if (i < 425984) { j = i - 393216; K = 512; N = 64;  S0 = Wo2; }
    else if (i < 491520) { j = i - 425984; K = 256; N = 256; S0 = Wv; }
    else                 { j = i - 491520; K = 256; N = 256; S0 = Wout; }
    int tile = j >> 9, r = j & 511;
    int lane = r >> 3, e = r & 7;
    int q4 = lane >> 4, r16 = lane & 15;
    int KC = K >> 5;
    int nc = tile / KC, kc = tile - nc * KC;
    int k = kc * 32 + q4 * 8 + e;
    int n = nc * 16 + r16;
    float v;
    if (S1 && k >= 256) v = S1[(size_t)(k - 256) * N + n];
    else                v = S0[(size_t)k * N + n];
    ws[i] = (__bf16)v;
}

// ============ fused kernel: MT=64, 1024 threads (16 waves), 128KB LDS, 1 block/CU ============
extern "C" __global__ void __launch_bounds__(1024, 4)
fused_ext_attn(const float* __restrict__ query, const float* __restrict__ key,
               const float* __restrict__ value, const float* __restrict__ refp,
               const float* __restrict__ pose,
               const __bf16* __restrict__ ws,
               const float* __restrict__ bq, const float* __restrict__ bk,
               const float* __restrict__ bv, const float* __restrict__ bpos,
               const float* __restrict__ bo1, const float* __restrict__ bo2,
               const float* __restrict__ bout,
               float* __restrict__ out)
{
    const __bf16* WTqp  = ws;             // KC=16
    const __bf16* WTkp  = ws + 131072;    // KC=16
    const __bf16* WTo1  = ws + 262144;    // KC=8
    const __bf16* WTo2  = ws + 393216;    // KC=16
    const __bf16* WTv   = ws + 425984;    // KC=8
    const __bf16* WTout = ws + 491520;    // KC=8

    __shared__ __attribute__((aligned(16))) __bf16 SA[MT * CC];   // query -> value
    __shared__ __attribute__((aligned(16))) __bf16 SB[MT * CC];   // pose -> o
    __shared__ __attribute__((aligned(16))) char   H1[65536];     // h1[64][512] -> key+off+qk+wv

    __bf16* keyb    = (__bf16*)H1;            // [64][256] bf16 swz (after B3)
    float*  off_s   = (float*)(H1 + 32768);   // [64][64]
    float*  qk_part = (float*)(H1 + 49152);   // [64][16]
    float*  wv_s    = (float*)(H1 + 53248);   // [64][8]

    const int tid = threadIdx.x;
    const int lane = tid & 63;
    const int wid = tid >> 6;        // 0..15 — wave owns 16 output cols in N=256 phases
    const int r16 = lane & 15;
    const int q4 = lane >> 4;
    const int laneoff = lane * 8;
    const int row0 = blockIdx.x * MT;

    // ---- P1: issue query+pose loads; stage query -> SA ----
    f32x4 vq[4], vp[4];
    stage_load(query, row0, tid, vq);
    stage_load(pose, row0, tid, vp);
    stage_write(SA, tid, vq);
    __syncthreads();                                   // B1

    // ---- P2: h1 = relu(query@Wo1+bo1), one 512-col pass (wave owns 32 cols) -> H1 ----
    {
        f32x4 acc[4][2];
#pragma unroll
        for (int i = 0; i < 4; ++i)
#pragma unroll
            for (int j = 0; j < 2; ++j) acc[i][j] = (f32x4){0.f, 0.f, 0.f, 0.f};
#pragma unroll
        for (int ks = 0; ks < 8; ++ks) {
            int ak = ks * 32 + q4 * 8;
            bf16x8 a[4], b[2];
#pragma unroll
            for (int mf = 0; mf < 4; ++mf)
                a[mf] = *(const bf16x8*)((const char*)SA + swz(mf * 16 + r16, ak));
#pragma unroll
            for (int nf = 0; nf < 2; ++nf)
                b[nf] = ldB(WTo1, wid * 2 + nf, 8, ks, laneoff);
#pragma unroll
            for (int mf = 0; mf < 4; ++mf)
#pragma unroll
                for (int nf = 0; nf < 2; ++nf)
                    acc[mf][nf] = __builtin_amdgcn_mfma_f32_16x16x32_bf16(a[mf], b[nf], acc[mf][nf], 0, 0, 0);
        }
#pragma unroll
        for (int mf = 0; mf < 4; ++mf)
#pragma unroll
            for (int nf = 0; nf < 2; ++nf) {
                int col = wid * 32 + nf * 16 + r16;
                float bias = bo1[col];
#pragma unroll
                for (int r = 0; r < 4; ++r)
                    *(__bf16*)(H1 + swzH(mf * 16 + q4 * 4 + r, col)) =
                        (__bf16)fmaxf(acc[mf][nf][r] + bias, 0.f);
            }
    }
    __syncthreads();                                   // B2

    // ---- P3: issue key loads; retire pose -> SB; off-GEMM on waves 0-3 (K=512) ----
    f32x4 vkey[4];
    stage_load(key, row0, tid, vkey);
    stage_write(SB, tid, vp);
    f32x4 accO[4];
#pragma unroll
    for (int i = 0; i < 4; ++i) accO[i] = (f32x4){0.f, 0.f, 0.f, 0.f};
    if (wid < 4) {
#pragma unroll
        for (int ks = 0; ks < 16; ++ks) {
            int ak = ks * 32 + q4 * 8;
            bf16x8 b = ldB(WTo2, wid, 16, ks, laneoff);
#pragma unroll
            for (int mf = 0; mf < 4; ++mf) {
                bf16x8 a = *(const bf16x8*)(H1 + swzH(mf * 16 + r16, ak));
                accO[mf] = __builtin_amdgcn_mfma_f32_16x16x32_bf16(a, b, accO[mf], 0, 0, 0);
            }
        }
    }
    __syncthreads();                                   // B3 (H1 fully dead)

    // ---- P4: retire key -> keyb; waves 0-3 write off_s; q-GEMM (K=512, wave cols 16w) ----
    stage_write(keyb, tid, vkey);
    if (wid < 4) {
        int col = wid * 16 + r16;
        float b2 = bo2[col];
#pragma unroll
        for (int mf = 0; mf < 4; ++mf)
#pragma unroll
            for (int r = 0; r < 4; ++r)
                off_s[(mf * 16 + q4 * 4 + r) * 64 + col] = accO[mf][r] + b2;
    }
    f32x4 qa[4];
#pragma unroll
    for (int i = 0; i < 4; ++i) qa[i] = (f32x4){0.f, 0.f, 0.f, 0.f};
#pragma unroll
    for (int ks = 0; ks < 16; ++ks) {
        int ak = (ks & 7) * 32 + q4 * 8;
        const char* Abase = (ks < 8) ? (const char*)SA : (const char*)SB;
        bf16x8 b = ldB(WTqp, wid, 16, ks, laneoff);
#pragma unroll
        for (int mf = 0; mf < 4; ++mf) {
            bf16x8 a = *(const bf16x8*)(Abase + swz(mf * 16 + r16, ak));
            qa[mf] = __builtin_amdgcn_mfma_f32_16x16x32_bf16(a, b, qa[mf], 0, 0, 0);
        }
    }
    __syncthreads();                                   // B4 (keyb staged; SA dead)

    // ---- P5: issue value loads; k-GEMM (K=512); in-reg dot -> qk_part ----
    f32x4 vval[4];
    stage_load(value, row0, tid, vval);
    {
        f32x4 ka[4];
#pragma unroll
        for (int i = 0; i < 4; ++i) ka[i] = (f32x4){0.f, 0.f, 0.f, 0.f};
#pragma unroll
        for (int ks = 0; ks < 16; ++ks) {
            int ak = (ks & 7) * 32 + q4 * 8;
            const char* Abase = (ks < 8) ? (const char*)keyb : (const char*)SB;
            bf16x8 b = ldB(WTkp, wid, 16, ks, laneoff);
#pragma unroll
            for (int mf = 0; mf < 4; ++mf) {
                bf16x8 a = *(const bf16x8*)(Abase + swz(mf * 16 + r16, ak));
                ka[mf] = __builtin_amdgcn_mfma_f32_16x16x32_bf16(a, b, ka[mf], 0, 0, 0);
            }
        }
        int col = wid * 16 + r16;
        float Bq = bq[col] + bpos[col];
        float Bk = bk[col] + bpos[col];
#pragma unroll
        for (int mf = 0; mf < 4; ++mf)
#pragma unroll
            for (int r = 0; r < 4; ++r) {
                float p = (qa[mf][r] + Bq) * (ka[mf][r] + Bk);
#pragma unroll
                for (int m = 1; m < 16; m <<= 1)
                    p += __shfl_xor(p, m);
                if (r16 == 0)
                    qk_part[(mf * 16 + q4 * 4 + r) * 16 + wid] = p;
            }
    }
    __syncthreads();                                   // B5

    // ---- P6: retire value -> SA; softmax on first 512 threads -> wv_s ----
    stage_write(SA, tid, vval);
    if (tid < 512) {
        int t = tid >> 3, h = tid & 7;
        float qk = qk_part[t * 16 + h * 2] + qk_part[t * 16 + h * 2 + 1];
        f32x2 rp = __builtin_nontemporal_load((const f32x2*)(refp + (size_t)(row0 + t) * 2));
        float wgt[4], lg[4];
        float m = -1e30f;
#pragma unroll
        for (int kk = 0; kk < 4; ++kk) {
            float ox = off_s[t * 64 + (h * 4 + kk) * 2];
            float oy = off_s[t * 64 + (h * 4 + kk) * 2 + 1];
            float cx = rp[0] + ox - 0.5f, cy = rp[1] + oy - 0.5f;
            float wx = fmaxf(0.f, 1.f - fabsf(cx));
            float wy = fmaxf(0.f, 1.f - fabsf(cy));
            wgt[kk] = wx * wy;
            lg[kk] = qk * wgt[kk] * 0.17677669529663687f;  // 1/sqrt(32)
            m = fmaxf(m, lg[kk]);
        }
        float s = 0.f, sw = 0.f;
#pragma unroll
        for (int kk = 0; kk < 4; ++kk) {
            float e = __expf(lg[kk] - m);
            s += e;
            sw += e * wgt[kk];
        }
        wv_s[t * 8 + h] = sw / s;
    }
    __syncthreads();                                   // B6

    // ---- P7: o = (value@Wv + bv) * wv -> SB ----
    {
        f32x4 acc[4];
#pragma unroll
        for (int i = 0; i < 4; ++i) acc[i] = (f32x4){0.f, 0.f, 0.f, 0.f};
#pragma unroll
        for (int ks = 0; ks < 8; ++ks) {
            int ak = ks * 32 + q4 * 8;
            bf16x8 b = ldB(WTv, wid, 8, ks, laneoff);
#pragma unroll
            for (int mf = 0; mf < 4; ++mf) {
                bf16x8 a = *(const bf16x8*)((const char*)SA + swz(mf * 16 + r16, ak));
                acc[mf] = __builtin_amdgcn_mfma_f32_16x16x32_bf16(a, b, acc[mf], 0, 0, 0);
            }
        }
        int col = wid * 16 + r16;
        float bias = bv[col];
        int head = wid >> 1;
#pragma unroll
        for (int mf = 0; mf < 4; ++mf)
#pragma unroll
            for (int r = 0; r < 4; ++r) {
                int row = mf * 16 + q4 * 4 + r;
                float wvv = wv_s[row * 8 + head];
                *(__bf16*)((char*)SB + swz(row, col)) = (__bf16)((acc[mf][r] + bias) * wvv);
            }
    }
    __syncthreads();                                   // B7

    // ---- P8: out = o @ WTout + bout -> global (NT store) ----
    {
        f32x4 acc[4];
#pragma unroll
        for (int i = 0; i < 4; ++i) acc[i] = (f32x4){0.f, 0.f, 0.f, 0.f};
#pragma unroll
        for (int ks = 0; ks < 8; ++ks) {
            int ak = ks * 32 + q4 * 8;
            bf16x8 b = ldB(WTout, wid, 8, ks, laneoff);
#pragma unroll
            for (int mf = 0; mf < 4; ++mf) {
                bf16x8 a = *(const bf16x8*)((const char*)SB + swz(mf * 16 + r16, ak));
                acc[mf] = __builtin_amdgcn_mfma_f32_16x16x32_bf16(a, b, acc[mf], 0, 0, 0);
            }
        }
        int col = wid * 16 + r16;
        float bias = bout[col];
#pragma unroll
        for (int mf = 0; mf < 4; ++mf)
#pragma unroll
            for (int r = 0; r < 4; ++r) {
                int row = mf * 16 + q4 * 4 + r;
                __builtin_nontemporal_store(acc[mf][r] + bias,
                                            out + (size_t)(row0 + row) * CC + col);
            }
    }
}

extern "C" void kernel_launch(void* const* d_in, const int* in_sizes, int n_in,
                              void* d_out, int out_size, void* d_ws, size_t ws_size,
                              hipStream_t stream)
{
    const float* query = (const float*)d_in[0];
    const float* key   = (const float*)d_in[1];
    const float* value = (const float*)d_in[2];
    const float* refp  = (const float*)d_in[3];
    const float* pose  = (const float*)d_in[4];
    const float* Wq  = (const float*)d_in[5];  const float* bq   = (const float*)d_in[6];
    const float* Wk  = (const float*)d_in[7];  const float* bk   = (const float*)d_in[8];
    const float* Wv  = (const float*)d_in[9];  const float* bv   = (const float*)d_in[10];
    const float* Wo1 = (const float*)d_in[11]; const float* bo1  = (const float*)d_in[12];
    const float* Wo2 = (const float*)d_in[13]; const float* bo2  = (const float*)d_in[14];
    const float* Wpos= (const float*)d_in[15]; const float* bpos = (const float*)d_in[16];
    const float* Wout= (const float*)d_in[17]; const float* bout = (const float*)d_in[18];

    __bf16* ws = (__bf16*)d_ws;

    prep_all<<<2176, 256, 0, stream>>>(Wq, Wk, Wpos, Wo1, Wo2, Wv, Wout, ws);

    fused_ext_attn<<<65536 / MT, 1024, 0, stream>>>(
        query, key, value, refp, pose, ws,
        bq, bk, bv, bpos, bo1, bo2, bout, (float*)d_out);
}

// Round 15
// 195.401 us; speedup vs baseline: 1.0006x; 1.0006x over previous
//
#include <hip/hip_runtime.h>
#include <hip/hip_bf16.h>

typedef __bf16 bf16x8 __attribute__((ext_vector_type(8)));
typedef float f32x4 __attribute__((ext_vector_type(4)));
typedef float f32x2 __attribute__((ext_vector_type(2)));

#define MT 64   // tokens per block
#define CC 256

// swizzled LDS byte offset, [.][256] bf16 tile (row stride 512B)
__device__ __forceinline__ int swz(int r, int c) {
    return r * 512 + ((c * 2) ^ ((r & 7) << 4));
}
// swizzled LDS byte offset, [.][512] bf16 tile (row stride 1024B)
__device__ __forceinline__ int swzH(int r, int c) {
    return r * 1024 + ((c * 2) ^ ((r & 7) << 4));
}

// packed-B fragment load: tile (nc, kc) of 16 cols x 32 k, 1KB contiguous
__device__ __forceinline__ bf16x8 ldB(const __bf16* __restrict__ WT, int nc, int KC, int kc,
                                      int laneoff) {
    return *(const bf16x8*)(WT + ((size_t)nc * KC + kc) * 512 + laneoff);
}

// 1024-thread staging of a 64x256 fp32 tile: 4 f32x4 per thread (NT loads)
__device__ __forceinline__ void stage_load(const float* __restrict__ src, int row0, int tid,
                                           f32x4 (&v)[4]) {
#pragma unroll
    for (int i = 0; i < 4; ++i) {
        int f = i * 1024 + tid;
        int r = f >> 6;
        int c = (f & 63) * 4;
        v[i] = __builtin_nontemporal_load((const f32x4*)(src + (size_t)(row0 + r) * CC + c));
    }
}
__device__ __forceinline__ void stage_write(__bf16* dst, int tid, const f32x4 (&v)[4]) {
#pragma unroll
    for (int i = 0; i < 4; ++i) {
        int f = i * 1024 + tid;
        int r = f >> 6;
        int c = (f & 63) * 4;
        union { __bf16 h[4]; unsigned long long u; } uu;
        uu.h[0] = (__bf16)v[i][0]; uu.h[1] = (__bf16)v[i][1];
        uu.h[2] = (__bf16)v[i][2]; uu.h[3] = (__bf16)v[i][3];
        *(unsigned long long*)((char*)dst + swz(r, c)) = uu.u;
    }
}

// weight prep: transpose + bf16 + FRAGMENT-PACK (16col x 32k tiles = 1KB contiguous,
// element order lane*8+e). layout (bf16 elem offsets):
//   WTqp @0 (K=512,N=256: k<256 Wq else Wpos) | WTkp @131072 (Wk/Wpos)
//   WTo1 @262144 (K=256,N=512) | WTo2 @393216 (K=512,N=64)
//   WTv @425984 (K=256,N=256) | WTout @491520 (K=256,N=256)
__global__ void prep_all(const float* __restrict__ Wq, const float* __restrict__ Wk,
                         const float* __restrict__ Wpos, const float* __restrict__ Wo1,
                         const float* __restrict__ Wo2, const float* __restrict__ Wv,
                         const float* __restrict__ Wout, __bf16* __restrict__ ws)
{
    int i = blockIdx.x * 256 + threadIdx.x;
    if (i >= 557056) return;
    int j, K, N;
    const float* S0 = nullptr; const float* S1 = nullptr;
    if (i < 131072)      { j = i;          K = 512; N = 256; S0 = Wq;  S1 = Wpos; }
    else if (i < 262144) { j = i - 131072; K = 512; N = 256; S0 = Wk;  S1 = Wpos; }
    else if (i < 393216) { j = i - 262144; K = 256; N = 512; S0 = Wo1; }
    else if (i < 425984) { j = i - 393216; K = 512; N = 64;  S0 = Wo2; }
    else if (i < 491520) { j = i - 425984; K = 256; N = 256; S0 = Wv; }
    else                 { j = i - 491520; K = 256; N = 256; S0 = Wout; }
    int tile = j >> 9, r = j & 511;
    int lane = r >> 3, e = r & 7;
    int q4 = lane >> 4, r16 = lane & 15;
    int KC = K >> 5;
    int nc = tile / KC, kc = tile - nc * KC;
    int k = kc * 32 + q4 * 8 + e;
    int n = nc * 16 + r16;
    float v;
    if (S1 && k >= 256) v = S1[(size_t)(k - 256) * N + n];
    else                v = S0[(size_t)k * N + n];
    ws[i] = (__bf16)v;
}

// ============ fused kernel: MT=64, 1024 threads (16 waves), 128KB LDS, 1 block/CU ============
// NOTE: __launch_bounds__ 2nd arg behaves as CUDA min-BLOCKS-per-CU on this toolchain:
// (1024,1) -> 16 waves/CU -> 128-VGPR cap (fits ~100-VGPR budget, no spill).
extern "C" __global__ void __launch_bounds__(1024, 1)
fused_ext_attn(const float* __restrict__ query, const float* __restrict__ key,
               const float* __restrict__ value, const float* __restrict__ refp,
               const float* __restrict__ pose,
               const __bf16* __restrict__ ws,
               const float* __restrict__ bq, const float* __restrict__ bk,
               const float* __restrict__ bv, const float* __restrict__ bpos,
               const float* __restrict__ bo1, const float* __restrict__ bo2,
               const float* __restrict__ bout,
               float* __restrict__ out)
{
    const __bf16* WTqp  = ws;             // KC=16
    const __bf16* WTkp  = ws + 131072;    // KC=16
    const __bf16* WTo1  = ws + 262144;    // KC=8
    const __bf16* WTo2  = ws + 393216;    // KC=16
    const __bf16* WTv   = ws + 425984;    // KC=8
    const __bf16* WTout = ws + 491520;    // KC=8

    __shared__ __attribute__((aligned(16))) __bf16 SA[MT * CC];   // query -> value
    __shared__ __attribute__((aligned(16))) __bf16 SB[MT * CC];   // pose -> o
    __shared__ __attribute__((aligned(16))) char   H1[65536];     // h1[64][512] -> key+off+qk+wv

    __bf16* keyb    = (__bf16*)H1;            // [64][256] bf16 swz (after B3)
    float*  off_s   = (float*)(H1 + 32768);   // [64][64]
    float*  qk_part = (float*)(H1 + 49152);   // [64][16]
    float*  wv_s    = (float*)(H1 + 53248);   // [64][8]

    const int tid = threadIdx.x;
    const int lane = tid & 63;
    const int wid = tid >> 6;        // 0..15 — wave owns 16 output cols in N=256 phases
    const int r16 = lane & 15;
    const int q4 = lane >> 4;
    const int laneoff = lane * 8;
    const int row0 = blockIdx.x * MT;

    // ---- P1: issue query+pose loads; stage query -> SA ----
    f32x4 vq[4], vp[4];
    stage_load(query, row0, tid, vq);
    stage_load(pose, row0, tid, vp);
    stage_write(SA, tid, vq);
    __syncthreads();                                   // B1

    // ---- P2: h1 = relu(query@Wo1+bo1), one 512-col pass (wave owns 32 cols) -> H1 ----
    {
        f32x4 acc[4][2];
#pragma unroll
        for (int i = 0; i < 4; ++i)
#pragma unroll
            for (int j = 0; j < 2; ++j) acc[i][j] = (f32x4){0.f, 0.f, 0.f, 0.f};
#pragma unroll
        for (int ks = 0; ks < 8; ++ks) {
            int ak = ks * 32 + q4 * 8;
            bf16x8 a[4], b[2];
#pragma unroll
            for (int mf = 0; mf < 4; ++mf)
                a[mf] = *(const bf16x8*)((const char*)SA + swz(mf * 16 + r16, ak));
#pragma unroll
            for (int nf = 0; nf < 2; ++nf)
                b[nf] = ldB(WTo1, wid * 2 + nf, 8, ks, laneoff);
#pragma unroll
            for (int mf = 0; mf < 4; ++mf)
#pragma unroll
                for (int nf = 0; nf < 2; ++nf)
                    acc[mf][nf] = __builtin_amdgcn_mfma_f32_16x16x32_bf16(a[mf], b[nf], acc[mf][nf], 0, 0, 0);
        }
#pragma unroll
        for (int mf = 0; mf < 4; ++mf)
#pragma unroll
            for (int nf = 0; nf < 2; ++nf) {
                int col = wid * 32 + nf * 16 + r16;
                float bias = bo1[col];
#pragma unroll
                for (int r = 0; r < 4; ++r)
                    *(__bf16*)(H1 + swzH(mf * 16 + q4 * 4 + r, col)) =
                        (__bf16)fmaxf(acc[mf][nf][r] + bias, 0.f);
            }
    }
    __syncthreads();                                   // B2

    // ---- P3: issue key loads; retire pose -> SB; off-GEMM on waves 0-3 (K=512) ----
    f32x4 vkey[4];
    stage_load(key, row0, tid, vkey);
    stage_write(SB, tid, vp);
    f32x4 accO[4];
#pragma unroll
    for (int i = 0; i < 4; ++i) accO[i] = (f32x4){0.f, 0.f, 0.f, 0.f};
    if (wid < 4) {
#pragma unroll
        for (int ks = 0; ks < 16; ++ks) {
            int ak = ks * 32 + q4 * 8;
            bf16x8 b = ldB(WTo2, wid, 16, ks, laneoff);
#pragma unroll
            for (int mf = 0; mf < 4; ++mf) {
                bf16x8 a = *(const bf16x8*)(H1 + swzH(mf * 16 + r16, ak));
                accO[mf] = __builtin_amdgcn_mfma_f32_16x16x32_bf16(a, b, accO[mf], 0, 0, 0);
            }
        }
    }
    __syncthreads();                                   // B3 (H1 fully dead)

    // ---- P4: retire key -> keyb; waves 0-3 write off_s; q-GEMM (K=512, wave cols 16w) ----
    stage_write(keyb, tid, vkey);
    if (wid < 4) {
        int col = wid * 16 + r16;
        float b2 = bo2[col];
#pragma unroll
        for (int mf = 0; mf < 4; ++mf)
#pragma unroll
            for (int r = 0; r < 4; ++r)
                off_s[(mf * 16 + q4 * 4 + r) * 64 + col] = accO[mf][r] + b2;
    }
    f32x4 qa[4];
#pragma unroll
    for (int i = 0; i < 4; ++i) qa[i] = (f32x4){0.f, 0.f, 0.f, 0.f};
#pragma unroll
    for (int ks = 0; ks < 16; ++ks) {
        int ak = (ks & 7) * 32 + q4 * 8;
        const char* Abase = (ks < 8) ? (const char*)SA : (const char*)SB;
        bf16x8 b = ldB(WTqp, wid, 16, ks, laneoff);
#pragma unroll
        for (int mf = 0; mf < 4; ++mf) {
            bf16x8 a = *(const bf16x8*)(Abase + swz(mf * 16 + r16, ak));
            qa[mf] = __builtin_amdgcn_mfma_f32_16x16x32_bf16(a, b, qa[mf], 0, 0, 0);
        }
    }
    __syncthreads();                                   // B4 (keyb staged; SA dead)

    // ---- P5: issue value loads; k-GEMM (K=512); in-reg dot -> qk_part ----
    f32x4 vval[4];
    stage_load(value, row0, tid, vval);
    {
        f32x4 ka[4];
#pragma unroll
        for (int i = 0; i < 4; ++i) ka[i] = (f32x4){0.f, 0.f, 0.f, 0.f};
#pragma unroll
        for (int ks = 0; ks < 16; ++ks) {
            int ak = (ks & 7) * 32 + q4 * 8;
            const char* Abase = (ks < 8) ? (const char*)keyb : (const char*)SB;
            bf16x8 b = ldB(WTkp, wid, 16, ks, laneoff);
#pragma unroll
            for (int mf = 0; mf < 4; ++mf) {
                bf16x8 a = *(const bf16x8*)(Abase + swz(mf * 16 + r16, ak));
                ka[mf] = __builtin_amdgcn_mfma_f32_16x16x32_bf16(a, b, ka[mf], 0, 0, 0);
            }
        }
        int col = wid * 16 + r16;
        float Bq = bq[col] + bpos[col];
        float Bk = bk[col] + bpos[col];
#pragma unroll
        for (int mf = 0; mf < 4; ++mf)
#pragma unroll
            for (int r = 0; r < 4; ++r) {
                float p = (qa[mf][r] + Bq) * (ka[mf][r] + Bk);
#pragma unroll
                for (int m = 1; m < 16; m <<= 1)
                    p += __shfl_xor(p, m);
                if (r16 == 0)
                    qk_part[(mf * 16 + q4 * 4 + r) * 16 + wid] = p;
            }
    }
    __syncthreads();                                   // B5

    // ---- P6: retire value -> SA; softmax on first 512 threads -> wv_s ----
    stage_write(SA, tid, vval);
    if (tid < 512) {
        int t = tid >> 3, h = tid & 7;
        float qk = qk_part[t * 16 + h * 2] + qk_part[t * 16 + h * 2 + 1];
        f32x2 rp = __builtin_nontemporal_load((const f32x2*)(refp + (size_t)(row0 + t) * 2));
        float wgt[4], lg[4];
        float m = -1e30f;
#pragma unroll
        for (int kk = 0; kk < 4; ++kk) {
            float ox = off_s[t * 64 + (h * 4 + kk) * 2];
            float oy = off_s[t * 64 + (h * 4 + kk) * 2 + 1];
            float cx = rp[0] + ox - 0.5f, cy = rp[1] + oy - 0.5f;
            float wx = fmaxf(0.f, 1.f - fabsf(cx));
            float wy = fmaxf(0.f, 1.f - fabsf(cy));
            wgt[kk] = wx * wy;
            lg[kk] = qk * wgt[kk] * 0.17677669529663687f;  // 1/sqrt(32)
            m = fmaxf(m, lg[kk]);
        }
        float s = 0.f, sw = 0.f;
#pragma unroll
        for (int kk = 0; kk < 4; ++kk) {
            float e = __expf(lg[kk] - m);
            s += e;
            sw += e * wgt[kk];
        }
        wv_s[t * 8 + h] = sw / s;
    }
    __syncthreads();                                   // B6

    // ---- P7: o = (value@Wv + bv) * wv -> SB ----
    {
        f32x4 acc[4];
#pragma unroll
        for (int i = 0; i < 4; ++i) acc[i] = (f32x4){0.f, 0.f, 0.f, 0.f};
#pragma unroll
        for (int ks = 0; ks < 8; ++ks) {
            int ak = ks * 32 + q4 * 8;
            bf16x8 b = ldB(WTv, wid, 8, ks, laneoff);
#pragma unroll
            for (int mf = 0; mf < 4; ++mf) {
                bf16x8 a = *(const bf16x8*)((const char*)SA + swz(mf * 16 + r16, ak));
                acc[mf] = __builtin_amdgcn_mfma_f32_16x16x32_bf16(a, b, acc[mf], 0, 0, 0);
            }
        }
        int col = wid * 16 + r16;
        float bias = bv[col];
        int head = wid >> 1;
#pragma unroll
        for (int mf = 0; mf < 4; ++mf)
#pragma unroll
            for (int r = 0; r < 4; ++r) {
                int row = mf * 16 + q4 * 4 + r;
                float wvv = wv_s[row * 8 + head];
                *(__bf16*)((char*)SB + swz(row, col)) = (__bf16)((acc[mf][r] + bias) * wvv);
            }
    }
    __syncthreads();                                   // B7

    // ---- P8: out = o @ WTout + bout -> global (NT store) ----
    {
        f32x4 acc[4];
#pragma unroll
        for (int i = 0; i < 4; ++i) acc[i] = (f32x4){0.f, 0.f, 0.f, 0.f};
#pragma unroll
        for (int ks = 0; ks < 8; ++ks) {
            int ak = ks * 32 + q4 * 8;
            bf16x8 b = ldB(WTout, wid, 8, ks, laneoff);
#pragma unroll
            for (int mf = 0; mf < 4; ++mf) {
                bf16x8 a = *(const bf16x8*)((const char*)SB + swz(mf * 16 + r16, ak));
                acc[mf] = __builtin_amdgcn_mfma_f32_16x16x32_bf16(a, b, acc[mf], 0, 0, 0);
            }
        }
        int col = wid * 16 + r16;
        float bias = bout[col];
#pragma unroll
        for (int mf = 0; mf < 4; ++mf)
#pragma unroll
            for (int r = 0; r < 4; ++r) {
                int row = mf * 16 + q4 * 4 + r;
                __builtin_nontemporal_store(acc[mf][r] + bias,
                                            out + (size_t)(row0 + row) * CC + col);
            }
    }
}

extern "C" void kernel_launch(void* const* d_in, const int* in_sizes, int n_in,
                              void* d_out, int out_size, void* d_ws, size_t ws_size,
                              hipStream_t stream)
{
    const float* query = (const float*)d_in[0];
    const float* key   = (const float*)d_in[1];
    const float* value = (const float*)d_in[2];
    const float* refp  = (const float*)d_in[3];
    const float* pose  = (const float*)d_in[4];
    const float* Wq  = (const float*)d_in[5];  const float* bq   = (const float*)d_in[6];
    const float* Wk  = (const float*)d_in[7];  const float* bk   = (const float*)d_in[8];
    const float* Wv  = (const float*)d_in[9];  const float* bv   = (const float*)d_in[10];
    const float* Wo1 = (const float*)d_in[11]; const float* bo1  = (const float*)d_in[12];
    const float* Wo2 = (const float*)d_in[13]; const float* bo2  = (const float*)d_in[14];
    const float* Wpos= (const float*)d_in[15]; const float* bpos = (const float*)d_in[16];
    const float* Wout= (const float*)d_in[17]; const float* bout = (const float*)d_in[18];

    __bf16* ws = (__bf16*)d_ws;

    prep_all<<<2176, 256, 0, stream>>>(Wq, Wk, Wpos, Wo1, Wo2, Wv, Wout, ws);

    fused_ext_attn<<<65536 / MT, 1024, 0, stream>>>(
        query, key, value, refp, pose, ws,
        bq, bk, bv, bpos, bo1, bo2, bout, (float*)d_out);
}